// Round 1
// baseline (14237.785 us; speedup 1.0000x reference)
//
#include <hip/hip_runtime.h>
#include <hip/hip_bf16.h>
#include <cstddef>

#define B_ 16
#define T_ 512
#define L_ 128
#define NSTEP 129
#define ENC_ 512
#define H_ 1024
#define E_ 512
#define V_ 10000
#define A_ 512
#define SOS_ 1

typedef __hip_bfloat16 bf16;
typedef __attribute__((ext_vector_type(4))) float f32x4;
typedef __attribute__((ext_vector_type(8))) short short8;

__device__ __forceinline__ float sigm(float x) { return 1.0f / (1.0f + expf(-x)); }

// ---------------- P0: zero init ----------------
__global__ void zero_kernel(float* __restrict__ p, int n4) {
    int i = blockIdx.x * blockDim.x + threadIdx.x;
    if (i < n4) {
        float4 z = {0.f, 0.f, 0.f, 0.f};
        *(float4*)(p + (size_t)i * 4) = z;
    }
}

// ---------------- P1: enc_proj = enc_out @ W_enc ----------------
// grid: 1024 blocks (b = bid>>6, t0 = (bid&63)*8), 256 threads
__global__ __launch_bounds__(256) void encproj_kernel(const float* __restrict__ enc_out,
                                                      const float* __restrict__ W_enc,
                                                      float* __restrict__ enc_proj) {
    __shared__ float se[8][512];
    int tid = threadIdx.x;
    int b = blockIdx.x >> 6;
    int t0 = (blockIdx.x & 63) * 8;
    // stage 8 encoder rows
    for (int i = 0; i < 4; ++i) {
        int idx4 = tid + i * 256;            // 0..1023
        int tt = idx4 >> 7, e4 = idx4 & 127;
        float4 v = *(const float4*)(enc_out + ((size_t)(b * T_ + t0 + tt)) * ENC_ + e4 * 4);
        *(float4*)(&se[tt][e4 * 4]) = v;
    }
    __syncthreads();
    int a1 = tid, a2 = tid + 256;
    float acc1[8], acc2[8];
#pragma unroll
    for (int i = 0; i < 8; ++i) { acc1[i] = 0.f; acc2[i] = 0.f; }
    for (int e = 0; e < 512; ++e) {
        float w1 = W_enc[e * A_ + a1];
        float w2 = W_enc[e * A_ + a2];
#pragma unroll
        for (int tt = 0; tt < 8; ++tt) {
            float xv = se[tt][e];
            acc1[tt] += xv * w1;
            acc2[tt] += xv * w2;
        }
    }
#pragma unroll
    for (int tt = 0; tt < 8; ++tt) {
        enc_proj[((size_t)(b * T_ + t0 + tt)) * A_ + a1] = acc1[tt];
        enc_proj[((size_t)(b * T_ + t0 + tt)) * A_ + a2] = acc2[tt];
    }
}

// ---------------- transpose: in[R][C] f32 -> out[C][R] (f32 or bf16) ----------------
__device__ __forceinline__ void cvt_store(float* p, float v) { *p = v; }
__device__ __forceinline__ void cvt_store(bf16* p, float v) { *p = __float2bfloat16(v); }

template <typename OT>
__global__ __launch_bounds__(256) void transpose_kernel(const float* __restrict__ in,
                                                        OT* __restrict__ out, int R, int C) {
    __shared__ float tile[32][33];
    int c0 = blockIdx.x * 32, r0 = blockIdx.y * 32;
    int tx = threadIdx.x & 31, ty = threadIdx.x >> 5;  // ty 0..7
#pragma unroll
    for (int i = 0; i < 4; ++i) {
        int r = r0 + ty + i * 8, c = c0 + tx;
        if (c < C) tile[ty + i * 8][tx] = in[(size_t)r * C + c];
    }
    __syncthreads();
#pragma unroll
    for (int i = 0; i < 4; ++i) {
        int c = c0 + ty + i * 8, r = r0 + tx;
        if (c < C) cvt_store(&out[(size_t)c * R + r], tile[tx][ty + i * 8]);
    }
}

// ---------------- LSTM cell kernel (MODE 0: layer0, MODE 1: layer1) ----------------
// grid 256 blocks x 256 threads; block bi handles h-slice [bi*4, bi*4+4), all 4 gates, all 16 b.
template <int MODE>
__global__ __launch_bounds__(256) void lstm_kernel(
    const float* __restrict__ Wih, const float* __restrict__ Whh, const float* __restrict__ bias,
    const float* __restrict__ embed, const int* __restrict__ ys,
    const float* __restrict__ ctx_prev,  // MODE0
    const float* __restrict__ srcA,      // MODE0: h0_prev ; MODE1: h0_new
    const float* __restrict__ srcB,      // MODE1: h1_prev
    float* __restrict__ cbuf, float* __restrict__ h_out,
    const float* __restrict__ h0_new_rd,  // MODE1 (for dec)
    float* __restrict__ decR, bf16* __restrict__ dec_allb, int t) {
    __shared__ float ldsX[16 * 516];
    __shared__ float ldsG[4][4][16];
    int tid = threadIdx.x;
    int bi = blockIdx.x;
    int lane = tid & 63, w = tid >> 6;
    int b = lane & 15, g = lane >> 4;
    int row = g * H_ + bi * 4 + w;
    f32x4 accv = {0.f, 0.f, 0.f, 0.f};

    for (int c = 0; c < 4; ++c) {
        __syncthreads();
        // stage 512-column chunk of input vector for all 16 b
        for (int i = 0; i < 8; ++i) {
            int idx = tid + i * 256;      // 0..2047
            int k4 = idx & 127, bb = idx >> 7;
            int k = k4 * 4;
            float4 v;
            if (MODE == 0) {
                if (c == 0) {
                    int y = (t == 0) ? SOS_ : ys[bb * L_ + (t - 1)];
                    v = *(const float4*)(embed + (size_t)y * E_ + k);
                } else if (c == 1) {
                    v = *(const float4*)(ctx_prev + bb * ENC_ + k);
                } else {
                    v = *(const float4*)(srcA + bb * H_ + (c & 1) * 512 + k);
                }
            } else {
                const float* sp = (c < 2) ? srcA : srcB;
                v = *(const float4*)(sp + bb * H_ + (c & 1) * 512 + k);
            }
            *(float4*)(ldsX + bb * 516 + k) = v;
        }
        __syncthreads();
        const float* W = (c >> 1) ? Whh : Wih;
        const float4* wp = (const float4*)(W + (size_t)row * 1024 + (c & 1) * 512);
        const float4* lx = (const float4*)(ldsX + b * 516);
#pragma unroll 8
        for (int k4 = 0; k4 < 128; ++k4) {
            float4 x = lx[k4];
            float4 wv = wp[k4];
            accv.x += wv.x * x.x;
            accv.y += wv.y * x.y;
            accv.z += wv.z * x.z;
            accv.w += wv.w * x.w;
        }
    }
    __syncthreads();
    ldsG[g][w][b] = accv.x + accv.y + accv.z + accv.w;
    __syncthreads();
    if (tid < 64) {
        int hl = tid >> 4, bb = tid & 15;
        int h = bi * 4 + hl;
        float gi = ldsG[0][hl][bb] + bias[h];
        float gf = ldsG[1][hl][bb] + bias[H_ + h];
        float gg = ldsG[2][hl][bb] + bias[2 * H_ + h];
        float go = ldsG[3][hl][bb] + bias[3 * H_ + h];
        float cold = cbuf[bb * H_ + h];
        float cn = sigm(gf) * cold + sigm(gi) * tanhf(gg);
        float hn = sigm(go) * tanhf(cn);
        cbuf[bb * H_ + h] = cn;
        h_out[bb * H_ + h] = hn;
        if (MODE == 1) {
            float d = hn + h0_new_rd[bb * H_ + h];
            decR[bb * H_ + h] = d;
            dec_allb[((size_t)t * 16 + bb) * H_ + h] = __float2bfloat16(d);
        }
    }
}

// ---------------- K3: s[b][a] = dec @ W_dec + b_att  (via W_decT[a][h]) ----------------
// grid 32 blocks x 256 thr; block covers 16 rows (a)
__global__ __launch_bounds__(256) void sgemv_kernel(const float* __restrict__ WdecT,
                                                    const float* __restrict__ decR,
                                                    const float* __restrict__ b_att,
                                                    float* __restrict__ sbuf) {
    __shared__ float ldsX[16 * 516];
    int tid = threadIdx.x;
    int bi = blockIdx.x;
    int lane = tid & 63, w = tid >> 6;
    int b = lane & 15, g = lane >> 4;
    int row = bi * 16 + g * 4 + w;  // a index
    f32x4 accv = {0.f, 0.f, 0.f, 0.f};
    for (int c = 0; c < 2; ++c) {
        __syncthreads();
        for (int i = 0; i < 8; ++i) {
            int idx = tid + i * 256;
            int k4 = idx & 127, bb = idx >> 7;
            float4 v = *(const float4*)(decR + bb * H_ + c * 512 + k4 * 4);
            *(float4*)(ldsX + bb * 516 + k4 * 4) = v;
        }
        __syncthreads();
        const float4* wp = (const float4*)(WdecT + (size_t)row * H_ + c * 512);
        const float4* lx = (const float4*)(ldsX + b * 516);
#pragma unroll 8
        for (int k4 = 0; k4 < 128; ++k4) {
            float4 x = lx[k4];
            float4 wv = wp[k4];
            accv.x += wv.x * x.x;
            accv.y += wv.y * x.y;
            accv.z += wv.z * x.z;
            accv.w += wv.w * x.w;
        }
    }
    float sum = accv.x + accv.y + accv.z + accv.w;
    sbuf[b * A_ + row] = sum + b_att[row];
}

// ---------------- K4: e[b][t] = v . tanh(proj + s) ; also zero ctx_next ----------------
// grid 2048 x 256 (one wave per (b,t))
__global__ __launch_bounds__(256) void att_e_kernel(const float* __restrict__ enc_proj,
                                                    const float* __restrict__ sbuf,
                                                    const float* __restrict__ v_att,
                                                    float* __restrict__ ebuf,
                                                    float* __restrict__ ctx_next) {
    int tid = threadIdx.x;
    int flat = blockIdx.x * 256 + tid;
    if (flat < B_ * ENC_) ctx_next[flat] = 0.f;
    int wid = blockIdx.x * 4 + (tid >> 6);
    int lane = tid & 63;
    int b = wid >> 9, t = wid & 511;
    const float4* p4 = (const float4*)(enc_proj + ((size_t)(b * T_ + t)) * A_);
    const float4* s4 = (const float4*)(sbuf + b * A_);
    const float4* v4 = (const float4*)(v_att);
    float part = 0.f;
#pragma unroll
    for (int i = 0; i < 2; ++i) {
        int k4 = lane + i * 64;
        float4 p = p4[k4], s = s4[k4], v = v4[k4];
        part += v.x * tanhf(p.x + s.x) + v.y * tanhf(p.y + s.y) + v.z * tanhf(p.z + s.z) +
                v.w * tanhf(p.w + s.w);
    }
    for (int off = 32; off; off >>= 1) part += __shfl_xor(part, off);
    if (lane == 0) ebuf[b * T_ + t] = part;
}

// ---------------- K6: softmax (redundant per block) + ctx accumulation ----------------
// grid 256 (16 b x 16 t-chunks) x 256 thr
__global__ __launch_bounds__(256) void att_ctx_kernel(const float* __restrict__ ebuf,
                                                      const int* __restrict__ enc_lens,
                                                      const float* __restrict__ enc_out,
                                                      float* __restrict__ ctx_next) {
    int b = blockIdx.x >> 4, tc = blockIdx.x & 15;
    int tid = threadIdx.x;
    int len = enc_lens[b];
    __shared__ float red[256];
    __shared__ float aw[32];
    int t1 = tid, t2 = tid + 256;
    float e1 = ebuf[b * T_ + t1], e2 = ebuf[b * T_ + t2];
    float m1 = (t1 < len) ? e1 : -3.0e38f;
    float m2 = (t2 < len) ? e2 : -3.0e38f;
    red[tid] = fmaxf(m1, m2);
    __syncthreads();
    for (int s2 = 128; s2; s2 >>= 1) {
        if (tid < s2) red[tid] = fmaxf(red[tid], red[tid + s2]);
        __syncthreads();
    }
    float M = red[0];
    __syncthreads();
    float x1 = (t1 < len) ? expf(e1 - M) : 0.f;
    float x2 = (t2 < len) ? expf(e2 - M) : 0.f;
    red[tid] = x1 + x2;
    __syncthreads();
    for (int s2 = 128; s2; s2 >>= 1) {
        if (tid < s2) red[tid] += red[tid + s2];
        __syncthreads();
    }
    float S = red[0];
    __syncthreads();
    if (tid < 32) {
        int t = tc * 32 + tid;
        aw[tid] = (t < len) ? expf(ebuf[b * T_ + t] - M) / S : 0.f;
    }
    __syncthreads();
    float a1 = 0.f, a2 = 0.f;
    int ee1 = tid, ee2 = tid + 256;
    for (int i = 0; i < 32; ++i) {
        float wgt = aw[i];
        const float* rowp = enc_out + ((size_t)(b * T_ + tc * 32 + i)) * ENC_;
        a1 += wgt * rowp[ee1];
        a2 += wgt * rowp[ee2];
    }
    atomicAdd(&ctx_next[b * ENC_ + ee1], a1);
    atomicAdd(&ctx_next[b * ENC_ + ee2], a2);
}

// ---------------- F0: ctx_all (f32) -> ctx_allb (bf16, row r = t*16+b) ----------------
__global__ __launch_bounds__(256) void f0_kernel(const float* __restrict__ ctx_all,
                                                 bf16* __restrict__ ctx_allb) {
    int idx = blockIdx.x * 256 + threadIdx.x;  // < 2064*512
    int r = idx >> 9, e = idx & 511;
    float v = ctx_all[((size_t)((r >> 4) + 1)) * (B_ * ENC_) + (r & 15) * ENC_ + e];
    ctx_allb[(size_t)r * ENC_ + e] = __float2bfloat16(v);
}

// ---------------- F1: avb = tanh(cat(dec,ctx) @ W_bn + b_bn)  (bf16 MFMA) ----------------
// grid (33, 8), 256 thr. A: [r][k<1024]=dec_allb, [k>=1024]=ctx_allb ; B: W_bnT [1024][1536]
__global__ __launch_bounds__(256) void f1_kernel(const bf16* __restrict__ decb,
                                                 const bf16* __restrict__ ctxb,
                                                 const bf16* __restrict__ WbnT,
                                                 const float* __restrict__ b_bn,
                                                 bf16* __restrict__ avb) {
    int tid = threadIdx.x, w = tid >> 6, lane = tid & 63;
    int lm = lane & 15, lk = (lane >> 4) * 8;
    int mrow = blockIdx.x * 64 + w * 16 + lm;
    int nb = blockIdx.y * 128;
    f32x4 acc[8];
#pragma unroll
    for (int i = 0; i < 8; ++i) acc[i] = (f32x4){0.f, 0.f, 0.f, 0.f};
    for (int k0 = 0; k0 < 1536; k0 += 32) {
        int kk = k0 + lk;
        short8 a;
        if (kk < 1024)
            a = *(const short8*)(decb + (size_t)mrow * 1024 + kk);
        else
            a = *(const short8*)(ctxb + (size_t)mrow * 512 + (kk - 1024));
#pragma unroll
        for (int ns = 0; ns < 8; ++ns) {
            int col = nb + ns * 16 + lm;
            short8 bf = *(const short8*)(WbnT + (size_t)col * 1536 + kk);
            acc[ns] = __builtin_amdgcn_mfma_f32_16x16x32_bf16(a, bf, acc[ns], 0, 0, 0);
        }
    }
#pragma unroll
    for (int ns = 0; ns < 8; ++ns) {
        int n = nb + ns * 16 + lm;
#pragma unroll
        for (int j = 0; j < 4; ++j) {
            int m = blockIdx.x * 64 + w * 16 + (lane >> 4) * 4 + j;
            if (m < NSTEP * B_) {
                float v = tanhf(acc[ns][j] + b_bn[n]);
                avb[(size_t)m * 1024 + n] = __float2bfloat16(v);
            }
        }
    }
}

// ---------------- F2: logits = avb @ W_out + b_out (bf16 MFMA) ----------------
// grid (33, 79), 256 thr. B: W_outT [10240 pad][1024]
__global__ __launch_bounds__(256) void f2_kernel(const bf16* __restrict__ avb,
                                                 const bf16* __restrict__ WoutT,
                                                 const float* __restrict__ b_out,
                                                 float* __restrict__ out) {
    int tid = threadIdx.x, w = tid >> 6, lane = tid & 63;
    int lm = lane & 15, lk = (lane >> 4) * 8;
    int mrow = blockIdx.x * 64 + w * 16 + lm;
    int nb = blockIdx.y * 128;
    f32x4 acc[8];
#pragma unroll
    for (int i = 0; i < 8; ++i) acc[i] = (f32x4){0.f, 0.f, 0.f, 0.f};
    for (int k0 = 0; k0 < 1024; k0 += 32) {
        int kk = k0 + lk;
        short8 a = *(const short8*)(avb + (size_t)mrow * 1024 + kk);
#pragma unroll
        for (int ns = 0; ns < 8; ++ns) {
            int col = nb + ns * 16 + lm;
            short8 bf = *(const short8*)(WoutT + (size_t)col * 1024 + kk);
            acc[ns] = __builtin_amdgcn_mfma_f32_16x16x32_bf16(a, bf, acc[ns], 0, 0, 0);
        }
    }
#pragma unroll
    for (int ns = 0; ns < 8; ++ns) {
        int n = nb + ns * 16 + lm;
#pragma unroll
        for (int j = 0; j < 4; ++j) {
            int m = blockIdx.x * 64 + w * 16 + (lane >> 4) * 4 + j;
            if (m < NSTEP * B_ && n < V_) {
                int tt = m >> 4, bb = m & 15;
                out[((size_t)bb * NSTEP + tt) * V_ + n] = acc[ns][j] + b_out[n];
            }
        }
    }
}

// ---------------- launch ----------------
extern "C" void kernel_launch(void* const* d_in, const int* in_sizes, int n_in, void* d_out,
                              int out_size, void* d_ws, size_t ws_size, hipStream_t stream) {
    const float* enc_out = (const float*)d_in[0];
    const int* enc_lens = (const int*)d_in[1];
    const int* ys = (const int*)d_in[2];
    const float* embed = (const float*)d_in[3];
    const float* W_ih0 = (const float*)d_in[4];
    const float* W_hh0 = (const float*)d_in[5];
    const float* b0 = (const float*)d_in[6];
    const float* W_ih1 = (const float*)d_in[7];
    const float* W_hh1 = (const float*)d_in[8];
    const float* b1 = (const float*)d_in[9];
    const float* W_enc = (const float*)d_in[10];
    const float* b_att = (const float*)d_in[11];
    const float* v_att = (const float*)d_in[12];
    const float* W_dec = (const float*)d_in[13];
    const float* W_bn = (const float*)d_in[14];
    const float* b_bn = (const float*)d_in[15];
    const float* W_out = (const float*)d_in[16];
    const float* b_out = (const float*)d_in[17];
    float* out = (float*)d_out;

    if (ws_size < (size_t)62 * 1024 * 1024) return;  // need ~59 MB

    float* ws = (float*)d_ws;
    size_t o = 0;
    float* enc_proj = ws + o; o += (size_t)B_ * T_ * A_;        // 4194304
    float* WdecT = ws + o;    o += (size_t)A_ * H_;             // 524288
    float* h0R0 = ws + o;     o += B_ * H_;                     // zero-group start
    float* h1R0 = ws + o;     o += B_ * H_;
    float* c0R = ws + o;      o += B_ * H_;
    float* c1R = ws + o;      o += B_ * H_;
    float* ctx_all = ws + o;  o += (size_t)(NSTEP + 1) * B_ * ENC_;  // slot0 in zero range
    float* h0R1 = ws + o;     o += B_ * H_;
    float* h1R1 = ws + o;     o += B_ * H_;
    float* decR = ws + o;     o += B_ * H_;
    float* sbuf = ws + o;     o += B_ * A_;
    float* ebuf = ws + o;     o += B_ * T_;
    bf16* bb = (bf16*)(ws + o);
    size_t ob = 0;
    bf16* dec_allb = bb + ob; ob += (size_t)2112 * 1024;
    bf16* ctx_allb = bb + ob; ob += (size_t)2112 * 512;
    bf16* avb = bb + ob;      ob += (size_t)2112 * 1024;
    bf16* WbnT = bb + ob;     ob += (size_t)1024 * 1536;
    bf16* WoutT = bb + ob;    ob += (size_t)10240 * 1024;

    float* h0buf[2] = {h0R0, h0R1};
    float* h1buf[2] = {h1R0, h1R1};

    // P-phase
    zero_kernel<<<72, 256, 0, stream>>>(h0R0, (4 * B_ * H_ + B_ * ENC_) / 4);
    encproj_kernel<<<1024, 256, 0, stream>>>(enc_out, W_enc, enc_proj);
    transpose_kernel<float><<<dim3(16, 32), 256, 0, stream>>>(W_dec, WdecT, H_, A_);
    transpose_kernel<bf16><<<dim3(32, 48), 256, 0, stream>>>(W_bn, WbnT, 1536, 1024);
    transpose_kernel<bf16><<<dim3(313, 32), 256, 0, stream>>>(W_out, WoutT, 1024, V_);

    for (int t = 0; t < NSTEP; ++t) {
        int cur = t & 1;
        lstm_kernel<0><<<256, 256, 0, stream>>>(
            W_ih0, W_hh0, b0, embed, ys, ctx_all + (size_t)t * B_ * ENC_, h0buf[cur], nullptr,
            c0R, h0buf[cur ^ 1], nullptr, nullptr, nullptr, t);
        lstm_kernel<1><<<256, 256, 0, stream>>>(
            W_ih1, W_hh1, b1, nullptr, nullptr, nullptr, h0buf[cur ^ 1], h1buf[cur], c1R,
            h1buf[cur ^ 1], h0buf[cur ^ 1], decR, dec_allb, t);
        sgemv_kernel<<<32, 256, 0, stream>>>(WdecT, decR, b_att, sbuf);
        att_e_kernel<<<2048, 256, 0, stream>>>(enc_proj, sbuf, v_att, ebuf,
                                               ctx_all + (size_t)(t + 1) * B_ * ENC_);
        att_ctx_kernel<<<256, 256, 0, stream>>>(ebuf, enc_lens, enc_out,
                                                ctx_all + (size_t)(t + 1) * B_ * ENC_);
    }

    f0_kernel<<<(NSTEP * B_ * ENC_) / 256, 256, 0, stream>>>(ctx_all, ctx_allb);
    f1_kernel<<<dim3(33, 8), 256, 0, stream>>>(dec_allb, ctx_allb, WbnT, b_bn, avb);
    f2_kernel<<<dim3(33, 79), 256, 0, stream>>>(avb, WoutT, b_out, out);
}

// Round 3
// 4855.546 us; speedup vs baseline: 2.9323x; 2.9323x over previous
//
#include <hip/hip_runtime.h>
#include <hip/hip_bf16.h>
#include <cstddef>

#define B_ 16
#define T_ 512
#define L_ 128
#define NSTEP 129
#define ENC_ 512
#define H_ 1024
#define E_ 512
#define V_ 10000
#define A_ 512
#define SOS_ 1

typedef __hip_bfloat16 bf16;
typedef __attribute__((ext_vector_type(4))) float f32x4;
typedef __attribute__((ext_vector_type(8))) short short8;

__device__ __forceinline__ float sigm(float x) { return 1.0f / (1.0f + expf(-x)); }
__device__ __forceinline__ unsigned int f2bu(float f) {
    bf16 h = __float2bfloat16(f);
    return (unsigned int)*(unsigned short*)&h;
}
__device__ __forceinline__ float bu2f(unsigned int u) { return __uint_as_float(u << 16); }

// ---------------- P0: zero init ----------------
__global__ void zero_kernel(float* __restrict__ p, int n4) {
    int i = blockIdx.x * blockDim.x + threadIdx.x;
    if (i < n4) {
        float4 z = {0.f, 0.f, 0.f, 0.f};
        *(float4*)(p + (size_t)i * 4) = z;
    }
}

// ---------------- P1: f32 -> bf16 bulk convert (n4 float4 groups) ----------------
__global__ __launch_bounds__(256) void cvt_bf16_kernel(const float* __restrict__ in,
                                                       bf16* __restrict__ out, int n4) {
    int i = blockIdx.x * 256 + threadIdx.x;
    if (i < n4) {
        float4 v = *(const float4*)(in + (size_t)i * 4);
        uint2 pk;
        pk.x = f2bu(v.x) | (f2bu(v.y) << 16);
        pk.y = f2bu(v.z) | (f2bu(v.w) << 16);
        *(uint2*)(out + (size_t)i * 4) = pk;
    }
}

// ---------------- transpose: in[R][C] f32 -> out[C][R] bf16 ----------------
__global__ __launch_bounds__(256) void transpose_kernel(const float* __restrict__ in,
                                                        bf16* __restrict__ out, int R, int C) {
    __shared__ float tile[32][33];
    int c0 = blockIdx.x * 32, r0 = blockIdx.y * 32;
    int tx = threadIdx.x & 31, ty = threadIdx.x >> 5;  // ty 0..7
#pragma unroll
    for (int i = 0; i < 4; ++i) {
        int r = r0 + ty + i * 8, c = c0 + tx;
        if (c < C) tile[ty + i * 8][tx] = in[(size_t)r * C + c];
    }
    __syncthreads();
#pragma unroll
    for (int i = 0; i < 4; ++i) {
        int c = c0 + ty + i * 8, r = r0 + tx;
        if (c < C) out[(size_t)c * R + r] = __float2bfloat16(tile[tx][ty + i * 8]);
    }
}

// ---------------- P2: pack LSTM weights to bf16, rows p = h*4 + gate ----------------
__global__ __launch_bounds__(256) void pack_lstm_kernel(const float* __restrict__ Wih,
                                                        const float* __restrict__ Whh,
                                                        const float* __restrict__ bsrc,
                                                        bf16* __restrict__ Wp,
                                                        float* __restrict__ bp) {
    int idx = blockIdx.x * 256 + threadIdx.x;  // over 4096*512
    int p = idx >> 9, k4 = idx & 511;
    int h = p >> 2, g = p & 3;
    int r = g * H_ + h;
    int k = k4 * 4;
    const float* src = (k < 1024) ? (Wih + (size_t)r * 1024 + k)
                                  : (Whh + (size_t)r * 1024 + (k - 1024));
    float4 v = *(const float4*)src;
    uint2 pk;
    pk.x = f2bu(v.x) | (f2bu(v.y) << 16);
    pk.y = f2bu(v.z) | (f2bu(v.w) << 16);
    *(uint2*)(Wp + (size_t)p * 2048 + k) = pk;
    if (k4 == 0) bp[p] = bsrc[r];
}

// ---------------- P3: enc_proj = enc_outb @ W_encT (bf16 MFMA) ----------------
// grid (128, 4): 64 rows x 128 cols per block
__global__ __launch_bounds__(256) void encproj_mfma(const bf16* __restrict__ Ab,
                                                    const bf16* __restrict__ Bt,
                                                    bf16* __restrict__ Cb) {
    int tid = threadIdx.x, w = tid >> 6, lane = tid & 63;
    int lm = lane & 15, hi = lane >> 4, lk = hi * 8;
    int mrow = blockIdx.x * 64 + w * 16 + lm;
    int nb = blockIdx.y * 128;
    f32x4 acc[8];
#pragma unroll
    for (int i = 0; i < 8; ++i) acc[i] = (f32x4){0.f, 0.f, 0.f, 0.f};
    for (int k0 = 0; k0 < 512; k0 += 32) {
        int kk = k0 + lk;
        short8 a = *(const short8*)(Ab + (size_t)mrow * 512 + kk);
#pragma unroll
        for (int ns = 0; ns < 8; ++ns) {
            int col = nb + ns * 16 + lm;
            short8 bf = *(const short8*)(Bt + (size_t)col * 512 + kk);
            acc[ns] = __builtin_amdgcn_mfma_f32_16x16x32_bf16(a, bf, acc[ns], 0, 0, 0);
        }
    }
#pragma unroll
    for (int ns = 0; ns < 8; ++ns) {
        int n = nb + ns * 16 + lm;
#pragma unroll
        for (int j = 0; j < 4; ++j) {
            int m = blockIdx.x * 64 + w * 16 + hi * 4 + j;
            Cb[(size_t)m * 512 + n] = __float2bfloat16(acc[ns][j]);
        }
    }
}

// ---------------- LSTM cell, bf16 MFMA. grid 256 blocks (4 h each), 256 thr ----------------
template <int MODE>
__global__ __launch_bounds__(256) void lstm_mfma(
    const bf16* __restrict__ Wp, const float* __restrict__ bp,
    const float* __restrict__ embed, const int* __restrict__ ys,
    const float* __restrict__ ctx_prev,  // MODE0
    const float* __restrict__ srcA,      // MODE0: h0_prev ; MODE1: h0_new
    const float* __restrict__ srcB,      // MODE1: h1_prev
    float* __restrict__ cbuf, float* __restrict__ h_out,
    bf16* __restrict__ dec_allb, int t) {
    __shared__ unsigned short xb[16 * 2048];  // 64KB; reused as reduce area after MFMA
    int tid = threadIdx.x;
    int w = tid >> 6, lane = tid & 63;
    int lm = lane & 15, hi = lane >> 4;

    // ---- stage x[16][2048] as bf16, XOR-swizzled (short off ^= (b&7)<<3) ----
    for (int c = 0; c < 4; ++c) {
        for (int i = 0; i < 8; ++i) {
            int idx = tid + i * 256;  // 0..2047
            int k4 = idx & 127, bb = idx >> 7;
            int k = k4 * 4;
            float4 v;
            if (MODE == 0) {
                if (c == 0) {
                    int y = (t == 0) ? SOS_ : ys[bb * L_ + (t - 1)];
                    v = *(const float4*)(embed + (size_t)y * E_ + k);
                } else if (c == 1) {
                    v = *(const float4*)(ctx_prev + bb * ENC_ + k);
                } else {
                    v = *(const float4*)(srcA + bb * H_ + (c - 2) * 512 + k);
                }
            } else {
                const float* sp = (c < 2) ? srcA : srcB;
                v = *(const float4*)(sp + bb * H_ + (c & 1) * 512 + k);
            }
            uint2 pk;
            pk.x = f2bu(v.x) | (f2bu(v.y) << 16);
            pk.y = f2bu(v.z) | (f2bu(v.w) << 16);
            int off = (bb * 2048 + c * 512 + k) ^ ((bb & 7) << 3);
            *(uint2*)(xb + off) = pk;
        }
    }
    __syncthreads();

    // ---- MFMA: wave w takes K-range [w*512, w*512+512) ----
    f32x4 acc = {0.f, 0.f, 0.f, 0.f};
    const bf16* wrow = Wp + ((size_t)(blockIdx.x * 16 + lm)) * 2048;
    int kw = w * 512 + hi * 8;
    int axr = (lm & 7) << 3;
#pragma unroll
    for (int ks = 0; ks < 16; ++ks) {
        int k = kw + ks * 32;
        short8 av = *(const short8*)(xb + ((lm * 2048 + k) ^ axr));
        short8 bv = *(const short8*)(wrow + k);
        acc = __builtin_amdgcn_mfma_f32_16x16x32_bf16(av, bv, acc, 0, 0, 0);
    }
    __syncthreads();  // xb no longer needed; reuse as reduce area
    float* red = (float*)xb;
    *(f32x4*)(red + (w * 64 + lane) * 4) = acc;
    __syncthreads();
    if (w == 0) {
        f32x4 s = acc;
#pragma unroll
        for (int ww = 1; ww < 4; ++ww) s += *(f32x4*)(red + (ww * 64 + lane) * 4);
        float bpv = bp[blockIdx.x * 16 + lm];
        float* g16 = red + 1024;
#pragma unroll
        for (int j = 0; j < 4; ++j) g16[lm * 16 + hi * 4 + j] = s[j] + bpv;
    }
    __syncthreads();
    if (tid < 64) {
        float* g16 = ((float*)xb) + 1024;
        int b = tid & 15, hl = tid >> 4;
        int h = blockIdx.x * 4 + hl;
        float gi = g16[(hl * 4 + 0) * 16 + b];
        float gf = g16[(hl * 4 + 1) * 16 + b];
        float gg = g16[(hl * 4 + 2) * 16 + b];
        float go = g16[(hl * 4 + 3) * 16 + b];
        float cold = cbuf[b * H_ + h];
        float cn = sigm(gf) * cold + sigm(gi) * tanhf(gg);
        float hn = sigm(go) * tanhf(cn);
        cbuf[b * H_ + h] = cn;
        h_out[b * H_ + h] = hn;
        if (MODE == 1) {
            float d = hn + srcA[b * H_ + h];  // srcA == h0_new
            dec_allb[((size_t)t * 16 + b) * H_ + h] = __float2bfloat16(d);
        }
    }
}

// ---------------- K3: sbuf = dec @ W_dec^T + b_att (bf16 MFMA), 32 blocks ----------------
__global__ __launch_bounds__(256) void sgemv_mfma(const bf16* __restrict__ WdT,
                                                  const bf16* __restrict__ decb,
                                                  const float* __restrict__ b_att,
                                                  float* __restrict__ sbuf, int t) {
    __shared__ float red[4 * 64 * 4];
    int tid = threadIdx.x, w = tid >> 6, lane = tid & 63;
    int lm = lane & 15, hi = lane >> 4;
    f32x4 acc = {0.f, 0.f, 0.f, 0.f};
    const bf16* arow = decb + ((size_t)t * 16 + lm) * 1024;
    const bf16* brow = WdT + ((size_t)(blockIdx.x * 16 + lm)) * 1024;
    int kw = w * 256 + hi * 8;
#pragma unroll
    for (int ks = 0; ks < 8; ++ks) {
        int k = kw + ks * 32;
        short8 av = *(const short8*)(arow + k);
        short8 bv = *(const short8*)(brow + k);
        acc = __builtin_amdgcn_mfma_f32_16x16x32_bf16(av, bv, acc, 0, 0, 0);
    }
    *(f32x4*)(red + (w * 64 + lane) * 4) = acc;
    __syncthreads();
    if (w == 0) {
        f32x4 s = acc;
#pragma unroll
        for (int ww = 1; ww < 4; ++ww) s += *(f32x4*)(red + (ww * 64 + lane) * 4);
        float ba = b_att[blockIdx.x * 16 + lm];
#pragma unroll
        for (int j = 0; j < 4; ++j)
            sbuf[(hi * 4 + j) * A_ + blockIdx.x * 16 + lm] = s[j] + ba;
    }
}

// ---------------- K4: e[b][t] = v . tanh(projb + s) ; also zero ctx_next ----------------
__global__ __launch_bounds__(256) void att_e_kernel(const bf16* __restrict__ projb,
                                                    const float* __restrict__ sbuf,
                                                    const float* __restrict__ v_att,
                                                    float* __restrict__ ebuf,
                                                    float* __restrict__ ctx_next) {
    int tid = threadIdx.x;
    int flat = blockIdx.x * 256 + tid;
    if (flat < B_ * ENC_) ctx_next[flat] = 0.f;
    int wid = blockIdx.x * 4 + (tid >> 6);
    int lane = tid & 63;
    int b = wid >> 9, t = wid & 511;
    short8 p8 = *(const short8*)(projb + ((size_t)(b * T_ + t)) * A_ + lane * 8);
    float4 s0 = *(const float4*)(sbuf + b * A_ + lane * 8);
    float4 s1 = *(const float4*)(sbuf + b * A_ + lane * 8 + 4);
    float4 v0 = *(const float4*)(v_att + lane * 8);
    float4 v1 = *(const float4*)(v_att + lane * 8 + 4);
    float part = 0.f;
    part += v0.x * tanhf(bu2f((unsigned short)p8[0]) + s0.x);
    part += v0.y * tanhf(bu2f((unsigned short)p8[1]) + s0.y);
    part += v0.z * tanhf(bu2f((unsigned short)p8[2]) + s0.z);
    part += v0.w * tanhf(bu2f((unsigned short)p8[3]) + s0.w);
    part += v1.x * tanhf(bu2f((unsigned short)p8[4]) + s1.x);
    part += v1.y * tanhf(bu2f((unsigned short)p8[5]) + s1.y);
    part += v1.z * tanhf(bu2f((unsigned short)p8[6]) + s1.z);
    part += v1.w * tanhf(bu2f((unsigned short)p8[7]) + s1.w);
    for (int off = 32; off; off >>= 1) part += __shfl_xor(part, off);
    if (lane == 0) ebuf[b * T_ + t] = part;
}

// ---------------- K6: softmax (redundant per block) + ctx accumulation (bf16 enc) ----------------
__global__ __launch_bounds__(256) void att_ctx_kernel(const float* __restrict__ ebuf,
                                                      const int* __restrict__ enc_lens,
                                                      const bf16* __restrict__ enc_outb,
                                                      float* __restrict__ ctx_next) {
    int b = blockIdx.x >> 4, tc = blockIdx.x & 15;
    int tid = threadIdx.x;
    int len = enc_lens[b];
    __shared__ float red[256];
    __shared__ float aw[32];
    int t1 = tid, t2 = tid + 256;
    float e1 = ebuf[b * T_ + t1], e2 = ebuf[b * T_ + t2];
    float m1 = (t1 < len) ? e1 : -3.0e38f;
    float m2 = (t2 < len) ? e2 : -3.0e38f;
    red[tid] = fmaxf(m1, m2);
    __syncthreads();
    for (int s2 = 128; s2; s2 >>= 1) {
        if (tid < s2) red[tid] = fmaxf(red[tid], red[tid + s2]);
        __syncthreads();
    }
    float M = red[0];
    __syncthreads();
    float x1 = (t1 < len) ? expf(e1 - M) : 0.f;
    float x2 = (t2 < len) ? expf(e2 - M) : 0.f;
    red[tid] = x1 + x2;
    __syncthreads();
    for (int s2 = 128; s2; s2 >>= 1) {
        if (tid < s2) red[tid] += red[tid + s2];
        __syncthreads();
    }
    float S = red[0];
    __syncthreads();
    if (tid < 32) {
        int t = tc * 32 + tid;
        aw[tid] = (t < len) ? expf(ebuf[b * T_ + t] - M) / S : 0.f;
    }
    __syncthreads();
    float a0 = 0.f, a1 = 0.f;
    int e0 = tid * 2;
    for (int i = 0; i < 32; ++i) {
        float wgt = aw[i];
        unsigned int u = *(const unsigned int*)(enc_outb + ((size_t)(b * T_ + tc * 32 + i)) * ENC_ + e0);
        a0 += wgt * bu2f(u & 0xffffu);
        a1 += wgt * bu2f(u >> 16);
    }
    atomicAdd(&ctx_next[b * ENC_ + e0], a0);
    atomicAdd(&ctx_next[b * ENC_ + e0 + 1], a1);
}

// ---------------- F0: ctx_all (f32) -> ctx_allb (bf16, row r = t*16+b) ----------------
__global__ __launch_bounds__(256) void f0_kernel(const float* __restrict__ ctx_all,
                                                 bf16* __restrict__ ctx_allb) {
    int idx = blockIdx.x * 256 + threadIdx.x;  // < 2064*512
    int r = idx >> 9, e = idx & 511;
    float v = ctx_all[((size_t)((r >> 4) + 1)) * (B_ * ENC_) + (r & 15) * ENC_ + e];
    ctx_allb[(size_t)r * ENC_ + e] = __float2bfloat16(v);
}

// ---------------- F1: avb = tanh(cat(dec,ctx) @ W_bn + b_bn)  (bf16 MFMA) ----------------
__global__ __launch_bounds__(256) void f1_kernel(const bf16* __restrict__ decb,
                                                 const bf16* __restrict__ ctxb,
                                                 const bf16* __restrict__ WbnT,
                                                 const float* __restrict__ b_bn,
                                                 bf16* __restrict__ avb) {
    int tid = threadIdx.x, w = tid >> 6, lane = tid & 63;
    int lm = lane & 15, lk = (lane >> 4) * 8;
    int mrow = blockIdx.x * 64 + w * 16 + lm;
    int nb = blockIdx.y * 128;
    f32x4 acc[8];
#pragma unroll
    for (int i = 0; i < 8; ++i) acc[i] = (f32x4){0.f, 0.f, 0.f, 0.f};
    for (int k0 = 0; k0 < 1536; k0 += 32) {
        int kk = k0 + lk;
        short8 a;
        if (kk < 1024)
            a = *(const short8*)(decb + (size_t)mrow * 1024 + kk);
        else
            a = *(const short8*)(ctxb + (size_t)mrow * 512 + (kk - 1024));
#pragma unroll
        for (int ns = 0; ns < 8; ++ns) {
            int col = nb + ns * 16 + lm;
            short8 bf = *(const short8*)(WbnT + (size_t)col * 1536 + kk);
            acc[ns] = __builtin_amdgcn_mfma_f32_16x16x32_bf16(a, bf, acc[ns], 0, 0, 0);
        }
    }
#pragma unroll
    for (int ns = 0; ns < 8; ++ns) {
        int n = nb + ns * 16 + lm;
#pragma unroll
        for (int j = 0; j < 4; ++j) {
            int m = blockIdx.x * 64 + w * 16 + (lane >> 4) * 4 + j;
            if (m < NSTEP * B_) {
                float v = tanhf(acc[ns][j] + b_bn[n]);
                avb[(size_t)m * 1024 + n] = __float2bfloat16(v);
            }
        }
    }
}

// ---------------- F2: logits = avb @ W_out + b_out (bf16 MFMA) ----------------
__global__ __launch_bounds__(256) void f2_kernel(const bf16* __restrict__ avb,
                                                 const bf16* __restrict__ WoutT,
                                                 const float* __restrict__ b_out,
                                                 float* __restrict__ out) {
    int tid = threadIdx.x, w = tid >> 6, lane = tid & 63;
    int lm = lane & 15, lk = (lane >> 4) * 8;
    int mrow = blockIdx.x * 64 + w * 16 + lm;
    int nb = blockIdx.y * 128;
    f32x4 acc[8];
#pragma unroll
    for (int i = 0; i < 8; ++i) acc[i] = (f32x4){0.f, 0.f, 0.f, 0.f};
    for (int k0 = 0; k0 < 1024; k0 += 32) {
        int kk = k0 + lk;
        short8 a = *(const short8*)(avb + (size_t)mrow * 1024 + kk);
#pragma unroll
        for (int ns = 0; ns < 8; ++ns) {
            int col = nb + ns * 16 + lm;
            short8 bf = *(const short8*)(WoutT + (size_t)col * 1024 + kk);
            acc[ns] = __builtin_amdgcn_mfma_f32_16x16x32_bf16(a, bf, acc[ns], 0, 0, 0);
        }
    }
#pragma unroll
    for (int ns = 0; ns < 8; ++ns) {
        int n = nb + ns * 16 + lm;
#pragma unroll
        for (int j = 0; j < 4; ++j) {
            int m = blockIdx.x * 64 + w * 16 + (lane >> 4) * 4 + j;
            if (m < NSTEP * B_ && n < V_) {
                int tt = m >> 4, bb = m & 15;
                out[((size_t)bb * NSTEP + tt) * V_ + n] = acc[ns][j] + b_out[n];
            }
        }
    }
}

// ---------------- launch ----------------
extern "C" void kernel_launch(void* const* d_in, const int* in_sizes, int n_in, void* d_out,
                              int out_size, void* d_ws, size_t ws_size, hipStream_t stream) {
    const float* enc_out = (const float*)d_in[0];
    const int* enc_lens = (const int*)d_in[1];
    const int* ys = (const int*)d_in[2];
    const float* embed = (const float*)d_in[3];
    const float* W_ih0 = (const float*)d_in[4];
    const float* W_hh0 = (const float*)d_in[5];
    const float* b0 = (const float*)d_in[6];
    const float* W_ih1 = (const float*)d_in[7];
    const float* W_hh1 = (const float*)d_in[8];
    const float* b1 = (const float*)d_in[9];
    const float* W_enc = (const float*)d_in[10];
    const float* b_att = (const float*)d_in[11];
    const float* v_att = (const float*)d_in[12];
    const float* W_dec = (const float*)d_in[13];
    const float* W_bn = (const float*)d_in[14];
    const float* b_bn = (const float*)d_in[15];
    const float* W_out = (const float*)d_in[16];
    const float* b_out = (const float*)d_in[17];
    float* out = (float*)d_out;

    if (ws_size < (size_t)92 * 1000 * 1000) return;  // need 91.6 MB exact

    float* ws = (float*)d_ws;
    size_t o = 0;
    float* h0R0 = ws + o;    o += B_ * H_;
    float* h1R0 = ws + o;    o += B_ * H_;
    float* c0R = ws + o;     o += B_ * H_;
    float* c1R = ws + o;     o += B_ * H_;
    float* ctx_all = ws + o; o += (size_t)(NSTEP + 1) * B_ * ENC_;
    float* h0R1 = ws + o;    o += B_ * H_;
    float* h1R1 = ws + o;    o += B_ * H_;
    float* sbuf = ws + o;    o += B_ * A_;
    float* ebuf = ws + o;    o += B_ * T_;
    float* bp0 = ws + o;     o += 4 * H_;
    float* bp1 = ws + o;     o += 4 * H_;

    bf16* bb = (bf16*)(ws + o);
    size_t ob = 0;
    bf16* enc_outb = bb + ob;  ob += (size_t)B_ * T_ * ENC_;     // 4,194,304
    bf16* enc_projb = bb + ob; ob += (size_t)B_ * T_ * A_;       // 4,194,304
    bf16* Wp0 = bb + ob;       ob += (size_t)4096 * 2048;        // 8,388,608
    bf16* Wp1 = bb + ob;       ob += (size_t)4096 * 2048;
    bf16* WencT = bb + ob;     ob += (size_t)A_ * ENC_;          // 262,144
    bf16* WdecT = bb + ob;     ob += (size_t)A_ * H_;            // 524,288
    bf16* dec_allb = bb + ob;  ob += (size_t)2112 * 1024;
    bf16* ctx_allb = bb + ob;  ob += (size_t)2112 * 512;
    bf16* avb = bb + ob;       ob += (size_t)2112 * 1024;
    bf16* WbnT = bb + ob;      ob += (size_t)1024 * 1536;
    bf16* WoutT = bb + ob;     ob += (size_t)10240 * 1024;

    float* h0buf[2] = {h0R0, h0R1};
    float* h1buf[2] = {h1R0, h1R1};

    // ---- P-phase ----
    zero_kernel<<<72, 256, 0, stream>>>(h0R0, (4 * B_ * H_ + B_ * ENC_) / 4);
    cvt_bf16_kernel<<<4096, 256, 0, stream>>>(enc_out, enc_outb, B_ * T_ * ENC_ / 4);
    transpose_kernel<<<dim3(16, 16), 256, 0, stream>>>(W_enc, WencT, ENC_, A_);
    transpose_kernel<<<dim3(16, 32), 256, 0, stream>>>(W_dec, WdecT, H_, A_);
    transpose_kernel<<<dim3(32, 48), 256, 0, stream>>>(W_bn, WbnT, H_ + ENC_, H_);
    transpose_kernel<<<dim3(313, 32), 256, 0, stream>>>(W_out, WoutT, H_, V_);
    pack_lstm_kernel<<<8192, 256, 0, stream>>>(W_ih0, W_hh0, b0, Wp0, bp0);
    pack_lstm_kernel<<<8192, 256, 0, stream>>>(W_ih1, W_hh1, b1, Wp1, bp1);
    encproj_mfma<<<dim3(128, 4), 256, 0, stream>>>(enc_outb, WencT, enc_projb);

    // ---- recurrence ----
    for (int t = 0; t < NSTEP; ++t) {
        int cur = t & 1;
        lstm_mfma<0><<<256, 256, 0, stream>>>(Wp0, bp0, embed, ys,
                                              ctx_all + (size_t)t * B_ * ENC_, h0buf[cur],
                                              nullptr, c0R, h0buf[cur ^ 1], nullptr, t);
        lstm_mfma<1><<<256, 256, 0, stream>>>(Wp1, bp1, nullptr, nullptr, nullptr,
                                              h0buf[cur ^ 1], h1buf[cur], c1R, h1buf[cur ^ 1],
                                              dec_allb, t);
        sgemv_mfma<<<32, 256, 0, stream>>>(WdecT, dec_allb, b_att, sbuf, t);
        att_e_kernel<<<2048, 256, 0, stream>>>(enc_projb, sbuf, v_att, ebuf,
                                               ctx_all + (size_t)(t + 1) * B_ * ENC_);
        att_ctx_kernel<<<256, 256, 0, stream>>>(ebuf, enc_lens, enc_outb,
                                                ctx_all + (size_t)(t + 1) * B_ * ENC_);
    }

    // ---- finals ----
    f0_kernel<<<(NSTEP * B_ * ENC_) / 256, 256, 0, stream>>>(ctx_all, ctx_allb);
    f1_kernel<<<dim3(33, 8), 256, 0, stream>>>(dec_allb, ctx_allb, WbnT, b_bn, avb);
    f2_kernel<<<dim3(33, 79), 256, 0, stream>>>(avb, WoutT, b_out, out);
}